// Round 4
// baseline (5926.756 us; speedup 1.0000x reference)
//
#include <hip/hip_runtime.h>
#include <hip/hip_bf16.h>
#include <stdint.h>

#define NN 50000
#define EE 800000
#define DD 128
#define LL 3

// ---------------- degree count ----------------
__global__ void deg_kernel(const int* __restrict__ dst, int* __restrict__ deg, int E) {
  int e = blockIdx.x * blockDim.x + threadIdx.x;
  if (e < E) atomicAdd(&deg[dst[e]], 1);
}

// ---------------- push-based scatter aggregation (fp32 atomics; exact segment_sum semantics) --
// one wave per edge: 64 lanes x float2 = 128 features
__global__ void scatter_kernel(const float* __restrict__ h, const int* __restrict__ srcv,
                               const int* __restrict__ dstv, float* __restrict__ agg, int E) {
  int e = blockIdx.x * 4 + (threadIdx.x >> 6);
  if (e >= E) return;
  int lane = threadIdx.x & 63;
  int s = srcv[e], d = dstv[e];
  float2 v = ((const float2*)(h + (size_t)s * 128))[lane];
  float* o = agg + (size_t)d * 128 + lane * 2;
  atomicAdd(o, v.x);
  atomicAdd(o + 1, v.y);
}

// ---------------- agg *= 1/max(deg,1) ----------------
__global__ void scale_kernel(float* __restrict__ agg, const int* __restrict__ deg, int n) {
  int i = blockIdx.x * blockDim.x + threadIdx.x;
  if (i < n) {
    int dg = deg[i >> 7];
    float inv = 1.0f / (float)(dg > 1 ? dg : 1);
    agg[i] *= inv;
  }
}

// ---------------- pure fp32 GEMM + bias + LayerNorm + ReLU ----------------
// one block (128 threads) per node; thread j computes output feature j.
// h2[j] = bias[j] + sum_k agg[k]*Wl[j][k] + sum_k h[k]*Wr[j][k]
// then LayerNorm (reference formula) + ReLU.
__global__ __launch_bounds__(128) void gemm_ln_f32_kernel(
    const float* __restrict__ agg, const float* __restrict__ h,
    const float* __restrict__ Wl, const float* __restrict__ Wr,  // [128][128] row-major (this layer)
    const float* __restrict__ bias, const float* __restrict__ gamma, const float* __restrict__ beta,
    float* __restrict__ out, int N) {
  int node = blockIdx.x;
  if (node >= N) return;
  int j = threadIdx.x;  // output feature
  __shared__ float sa[128];
  __shared__ float sh[128];
  __shared__ float rbuf[128];
  sa[j] = agg[(size_t)node * 128 + j];
  sh[j] = h[(size_t)node * 128 + j];
  __syncthreads();

  const float* wl = Wl + (size_t)j * 128;
  const float* wr = Wr + (size_t)j * 128;
  float acc = bias[j];
#pragma unroll 4
  for (int k = 0; k < 128; k++) {
    acc += sa[k] * wl[k];
    acc += sh[k] * wr[k];
  }

  // mean
  rbuf[j] = acc;
  __syncthreads();
#pragma unroll
  for (int s = 64; s > 0; s >>= 1) {
    if (j < s) rbuf[j] += rbuf[j + s];
    __syncthreads();
  }
  float mu = rbuf[0] * (1.0f / 128.0f);
  __syncthreads();

  // variance (reference formula: mean((h-mu)^2))
  float d = acc - mu;
  rbuf[j] = d * d;
  __syncthreads();
#pragma unroll
  for (int s = 64; s > 0; s >>= 1) {
    if (j < s) rbuf[j] += rbuf[j + s];
    __syncthreads();
  }
  float var = rbuf[0] * (1.0f / 128.0f);

  float y = d * rsqrtf(var + 1e-5f) * gamma[j] + beta[j];
  y = y > 0.0f ? y : 0.0f;
  out[(size_t)node * 128 + j] = y;
}

extern "C" void kernel_launch(void* const* d_in, const int* in_sizes, int n_in,
                              void* d_out, int out_size, void* d_ws, size_t ws_size,
                              hipStream_t stream) {
  const float* x = (const float*)d_in[0];
  const int* edge = (const int*)d_in[1];
  const float* Wl = (const float*)d_in[2];
  const float* bl = (const float*)d_in[3];
  const float* Wr = (const float*)d_in[4];
  const float* gamma = (const float*)d_in[5];
  const float* beta = (const float*)d_in[6];
  float* out = (float*)d_out;

  const int* srcv = edge;       // edge_index[0]
  const int* dstv = edge + EE;  // edge_index[1]

  char* p = (char*)d_ws;
  auto alloc = [&](size_t bytes) {
    char* r = p;
    p += (bytes + 255) & ~(size_t)255;
    return r;
  };
  const size_t fplane = (size_t)NN * 128 * 4;  // 25.6 MB fp32 plane
  float* hA = (float*)alloc(fplane);
  float* hB = (float*)alloc(fplane);
  float* agg_f = (float*)alloc(fplane);
  int* deg = (int*)alloc((size_t)NN * 4);
  if ((size_t)(p - (char*)d_ws) > ws_size) return;  // workspace too small: fail loudly

  hipMemsetAsync(deg, 0, (size_t)NN * 4, stream);
  deg_kernel<<<(EE + 255) / 256, 256, 0, stream>>>(dstv, deg, EE);

  const float* cur = x;
  float* nxt = hA;
  for (int l = 0; l < LL; l++) {
    hipMemsetAsync(agg_f, 0, fplane, stream);
    scatter_kernel<<<(EE + 3) / 4, 256, 0, stream>>>(cur, srcv, dstv, agg_f, EE);
    scale_kernel<<<(NN * 128 + 255) / 256, 256, 0, stream>>>(agg_f, deg, NN * 128);
    const float* Wl_l = Wl + (size_t)l * 128 * 128;
    const float* Wr_l = Wr + (size_t)l * 128 * 128;
    const float* bias = bl + (size_t)l * 128;
    const float* g = gamma + (size_t)l * 128;
    const float* b = beta + (size_t)l * 128;
    float* dst_buf = (l == LL - 1) ? out : nxt;
    gemm_ln_f32_kernel<<<NN, 128, 0, stream>>>(agg_f, cur, Wl_l, Wr_l, bias, g, b, dst_buf, NN);
    if (l < LL - 1) {
      cur = nxt;
      nxt = (nxt == hA) ? hB : hA;
    }
  }
}

// Round 5
// 561.878 us; speedup vs baseline: 10.5481x; 10.5481x over previous
//
#include <hip/hip_runtime.h>
#include <hip/hip_bf16.h>
#include <stdint.h>

#define NN 50000
#define EE 800000
#define DD 128
#define LL 3

// ---------------- CSR build ----------------
__global__ void deg_kernel(const int* __restrict__ dst, int* __restrict__ deg, int E) {
  int e = blockIdx.x * blockDim.x + threadIdx.x;
  if (e < E) atomicAdd(&deg[dst[e]], 1);
}

__global__ void scan_kernel(const int* __restrict__ deg, int* __restrict__ rowptr,
                            int* __restrict__ cursor, int N) {
  __shared__ int wsums[16];
  __shared__ int s_base;
  const int tid = threadIdx.x, lane = tid & 63, wid = tid >> 6;
  if (tid == 0) s_base = 0;
  __syncthreads();
  for (int start = 0; start < N; start += 1024) {
    int i = start + tid;
    int v = (i < N) ? deg[i] : 0;
    int x = v;
#pragma unroll
    for (int off = 1; off < 64; off <<= 1) {
      int y = __shfl_up(x, off, 64);
      if (lane >= off) x += y;
    }
    if (lane == 63) wsums[wid] = x;
    __syncthreads();
    if (wid == 0) {
      int w = (lane < 16) ? wsums[lane] : 0;
#pragma unroll
      for (int off = 1; off < 16; off <<= 1) {
        int y = __shfl_up(w, off, 64);
        if (lane >= off) w += y;
      }
      if (lane < 16) wsums[lane] = w;
    }
    __syncthreads();
    int base = s_base + (wid > 0 ? wsums[wid - 1] : 0);
    int excl = base + x - v;
    if (i < N) {
      rowptr[i] = excl;
      cursor[i] = excl;
    }
    __syncthreads();
    if (tid == 0) s_base += wsums[15];
    __syncthreads();
  }
  if (tid == 0) rowptr[N] = s_base;
}

__global__ void fill_kernel(const int* __restrict__ src, const int* __restrict__ dst,
                            int* __restrict__ cursor, int* __restrict__ col, int E) {
  int e = blockIdx.x * blockDim.x + threadIdx.x;
  if (e < E) {
    int d = dst[e];
    int pos = atomicAdd(&cursor[d], 1);
    col[pos] = src[e];
  }
}

// ---------------- CSR pull mean-aggregation: one wave per node, fp32 ----------------
__global__ __launch_bounds__(256) void agg_kernel(
    const float* __restrict__ h, const int* __restrict__ rowptr, const int* __restrict__ col,
    float* __restrict__ agg, int N) {
  int node = blockIdx.x * 4 + (threadIdx.x >> 6);
  if (node >= N) return;
  int lane = threadIdx.x & 63;
  int s = rowptr[node], e = rowptr[node + 1];
  float ax = 0.f, ay = 0.f;
  int i = s;
  for (; i + 1 < e; i += 2) {
    int s0 = col[i], s1 = col[i + 1];
    float2 v0 = ((const float2*)(h + (size_t)s0 * 128))[lane];
    float2 v1 = ((const float2*)(h + (size_t)s1 * 128))[lane];
    ax += v0.x + v1.x;
    ay += v0.y + v1.y;
  }
  if (i < e) {
    float2 v0 = ((const float2*)(h + (size_t)col[i] * 128))[lane];
    ax += v0.x;
    ay += v0.y;
  }
  int dg = e - s;
  float inv = 1.0f / (float)(dg > 1 ? dg : 1);
  float2 o;
  o.x = ax * inv;
  o.y = ay * inv;
  ((float2*)(agg + (size_t)node * 128))[lane] = o;
}

// ---------------- tiled fp32 GEMM ([agg|h] @ [Wl^T;Wr^T]) + bias + LayerNorm + ReLU -------
// 256 threads/block, 64 rows x 128 cols per block. Each thread: 4 rows x 8 cols register tile.
// K = 256 in 8 chunks of 32: As[64][36] (padded, 16B-aligned rows), Bs[32][128] = W^T chunk.
__global__ __launch_bounds__(256) void gemm_ln_f32_kernel(
    const float* __restrict__ agg, const float* __restrict__ h,
    const float* __restrict__ Wl, const float* __restrict__ Wr,  // [128][128] row-major, this layer
    const float* __restrict__ bias, const float* __restrict__ gamma, const float* __restrict__ beta,
    float* __restrict__ out, int N) {
  __shared__ __align__(16) float As[64][36];   // [row][k], +4 pad: bank-clean, rows 144 B (16B mult)
  __shared__ __align__(16) float Bs[32][128];  // [k][col]
  __shared__ float reds[64][16];
  __shared__ float redss[64][16];
  __shared__ float mu_s[64], rs_s[64];

  const int tid = threadIdx.x;
  const int cg = tid & 15;   // col group
  const int rg = tid >> 4;   // row group
  const int c0 = cg * 8;
  const int r0 = rg * 4;
  const int m0 = blockIdx.x * 64;

  float acc[4][8];
#pragma unroll
  for (int j = 0; j < 8; j++) {
    float bv = bias[c0 + j];
#pragma unroll
    for (int i = 0; i < 4; i++) acc[i][j] = bv;
  }

  const int st_row = tid & 63;          // A staging: row
  const int st_k = (tid >> 6) * 8;      // A staging: k offset within chunk
  int st_grow = m0 + st_row;
  if (st_grow >= N) st_grow = N - 1;    // clamp (rows independent; guarded at store)
  const int wj = tid >> 1;              // B staging: W row (= output col)
  const int wk = (tid & 1) * 16;        // B staging: k offset within chunk

  for (int kc = 0; kc < 8; kc++) {
    // stage A chunk: As[row][k] = Asrc[m0+row][kc*32 + k]
    {
      const float* srcA = (kc < 4) ? (agg + (size_t)st_grow * 128 + kc * 32 + st_k)
                                   : (h + (size_t)st_grow * 128 + (kc - 4) * 32 + st_k);
      float4 v0 = ((const float4*)srcA)[0];
      float4 v1 = ((const float4*)srcA)[1];
      *(float4*)&As[st_row][st_k] = v0;
      *(float4*)&As[st_row][st_k + 4] = v1;
    }
    // stage B chunk: Bs[k][j] = W[j][kc*32 + k]
    {
      const float* srcW = (kc < 4) ? (Wl + (size_t)wj * 128 + kc * 32 + wk)
                                   : (Wr + (size_t)wj * 128 + (kc - 4) * 32 + wk);
#pragma unroll
      for (int q = 0; q < 16; q++) Bs[wk + q][wj] = srcW[q];
    }
    __syncthreads();
#pragma unroll 8
    for (int k = 0; k < 32; k++) {
      float a0 = As[r0 + 0][k];
      float a1 = As[r0 + 1][k];
      float a2 = As[r0 + 2][k];
      float a3 = As[r0 + 3][k];
      float4 b0 = *(const float4*)&Bs[k][c0];
      float4 b1 = *(const float4*)&Bs[k][c0 + 4];
      float bv[8] = {b0.x, b0.y, b0.z, b0.w, b1.x, b1.y, b1.z, b1.w};
#pragma unroll
      for (int j = 0; j < 8; j++) {
        acc[0][j] += a0 * bv[j];
        acc[1][j] += a1 * bv[j];
        acc[2][j] += a2 * bv[j];
        acc[3][j] += a3 * bv[j];
      }
    }
    __syncthreads();
  }

  // ---- LayerNorm epilogue ----
#pragma unroll
  for (int i = 0; i < 4; i++) {
    float s = 0.f, ss = 0.f;
#pragma unroll
    for (int j = 0; j < 8; j++) {
      float v = acc[i][j];
      s += v;
      ss += v * v;
    }
    reds[r0 + i][cg] = s;
    redss[r0 + i][cg] = ss;
  }
  __syncthreads();
  if (tid < 64) {
    float s = 0.f, ss = 0.f;
#pragma unroll
    for (int g = 0; g < 16; g++) {
      s += reds[tid][g];
      ss += redss[tid][g];
    }
    float mu = s * (1.0f / 128.0f);
    float var = ss * (1.0f / 128.0f) - mu * mu;
    if (var < 0.f) var = 0.f;
    mu_s[tid] = mu;
    rs_s[tid] = rsqrtf(var + 1e-5f);
  }
  __syncthreads();

  float g_v[8], b_v[8];
#pragma unroll
  for (int j = 0; j < 8; j++) {
    g_v[j] = gamma[c0 + j];
    b_v[j] = beta[c0 + j];
  }
#pragma unroll
  for (int i = 0; i < 4; i++) {
    int row = m0 + r0 + i;
    if (row < N) {
      float mu = mu_s[r0 + i], rs = rs_s[r0 + i];
      float y[8];
#pragma unroll
      for (int j = 0; j < 8; j++) {
        float v = (acc[i][j] - mu) * rs * g_v[j] + b_v[j];
        y[j] = v > 0.f ? v : 0.f;
      }
      float4 o0 = {y[0], y[1], y[2], y[3]};
      float4 o1 = {y[4], y[5], y[6], y[7]};
      float* dst = out + (size_t)row * 128 + c0;
      ((float4*)dst)[0] = o0;
      ((float4*)dst)[1] = o1;
    }
  }
}

extern "C" void kernel_launch(void* const* d_in, const int* in_sizes, int n_in,
                              void* d_out, int out_size, void* d_ws, size_t ws_size,
                              hipStream_t stream) {
  const float* x = (const float*)d_in[0];
  const int* edge = (const int*)d_in[1];
  const float* Wl = (const float*)d_in[2];
  const float* bl = (const float*)d_in[3];
  const float* Wr = (const float*)d_in[4];
  const float* gamma = (const float*)d_in[5];
  const float* beta = (const float*)d_in[6];
  float* out = (float*)d_out;

  const int* srcv = edge;       // edge_index[0]
  const int* dstv = edge + EE;  // edge_index[1]

  char* p = (char*)d_ws;
  auto alloc = [&](size_t bytes) {
    char* r = p;
    p += (bytes + 255) & ~(size_t)255;
    return r;
  };
  const size_t fplane = (size_t)NN * 128 * 4;  // 25.6 MB fp32 plane
  float* hA = (float*)alloc(fplane);
  float* hB = (float*)alloc(fplane);
  float* agg_f = (float*)alloc(fplane);
  int* deg = (int*)alloc((size_t)NN * 4);
  int* cursor = (int*)alloc((size_t)NN * 4);
  int* rowptr = (int*)alloc((size_t)(NN + 1) * 4);
  int* colarr = (int*)alloc((size_t)EE * 4);
  if ((size_t)(p - (char*)d_ws) > ws_size) return;  // workspace too small: fail loudly

  hipMemsetAsync(deg, 0, (size_t)NN * 4, stream);
  deg_kernel<<<(EE + 255) / 256, 256, 0, stream>>>(dstv, deg, EE);
  scan_kernel<<<1, 1024, 0, stream>>>(deg, rowptr, cursor, NN);
  fill_kernel<<<(EE + 255) / 256, 256, 0, stream>>>(srcv, dstv, cursor, colarr, EE);

  const float* cur = x;
  float* nxt = hA;
  for (int l = 0; l < LL; l++) {
    agg_kernel<<<(NN + 3) / 4, 256, 0, stream>>>(cur, rowptr, colarr, agg_f, NN);
    const float* Wl_l = Wl + (size_t)l * 128 * 128;
    const float* Wr_l = Wr + (size_t)l * 128 * 128;
    const float* bias = bl + (size_t)l * 128;
    const float* g = gamma + (size_t)l * 128;
    const float* b = beta + (size_t)l * 128;
    float* dst_buf = (l == LL - 1) ? out : nxt;
    gemm_ln_f32_kernel<<<(NN + 63) / 64, 256, 0, stream>>>(
        agg_f, cur, Wl_l, Wr_l, bias, g, b, dst_buf, NN);
    if (l < LL - 1) {
      cur = nxt;
      nxt = (nxt == hA) ? hB : hA;
    }
  }
}